// Round 8
// baseline (298.684 us; speedup 1.0000x reference)
//
#include <hip/hip_runtime.h>

#define BS    64
#define CIN   128
#define OCH   128
#define HW    56
#define KEXP  8
#define KTOT  1152             // 9 * 128
#define NSTEP 36               // k-steps of 32
#define PLANEC 3364            // 58*58 16B-chunks per (b,quarter,octet) plane
#define WMIX_PS (NSTEP * OCH * 32)   // 147456 elems per sample
#define TPAD  60               // prep_xt LDS row stride (8B-aligned rows, conflict-free gather)

typedef __bf16 bf16x8 __attribute__((ext_vector_type(8)));
typedef __bf16 bf16x4 __attribute__((ext_vector_type(4)));
typedef float  f32x4  __attribute__((ext_vector_type(4)));

__device__ __forceinline__ unsigned f2bf(float f) {
    union { float f; unsigned u; } v; v.f = f;
    unsigned r = v.u + 0x7fffu + ((v.u >> 16) & 1u);   // RNE
    return r >> 16;
}

__device__ __forceinline__ void gl16(const unsigned short* g, unsigned short* l) {
    __builtin_amdgcn_global_load_lds(
        (const __attribute__((address_space(1))) void*)g,
        (__attribute__((address_space(3))) void*)l, 16, 0, 0);
}

// x [64][128][56][56] f32 -> x_t [64][qq=4][oct=4][58][58] chunks of 16 B
// (chunk = 8 channels c = qq*32+oct*8+k, bf16, zero halos).  (unchanged R7)
__global__ __launch_bounds__(256) void prep_xt(const float* __restrict__ x,
                                               unsigned short* __restrict__ xt) {
    __shared__ unsigned short t[CIN * TPAD];   // 15,360 B
    int b = blockIdx.x, ihp = blockIdx.y;      // ihp in [0,58)
    int tid = threadIdx.x;
    bool border = (ihp == 0) || (ihp == 57);
    if (!border) {
        int ih = ihp - 1;
        const float* xr = x + (size_t)b * CIN * HW * HW + (size_t)ih * HW;
        #pragma unroll
        for (int i7 = 0; i7 < 7; ++i7) {               // 1792 float4 = 7/thread
            int i = i7 * 256 + tid;
            int c = i / 14, w4 = i - c * 14;
            float4 v = *(const float4*)(xr + (size_t)c * (HW * HW) + w4 * 4);
            bf16x4 pk = { (__bf16)v.x, (__bf16)v.y, (__bf16)v.z, (__bf16)v.w };
            *(bf16x4*)&t[c * TPAD + w4 * 4] = pk;      // 8B aligned
        }
    }
    __syncthreads();
    for (int j = tid; j < 928; j += 256) {             // 4*4*58 chunks
        int qq = j / 232, rr = j - qq * 232;
        int oct = rr / 58, col = rr - oct * 58;
        union { unsigned short u[8]; uint4 v; } o;
        o.v = make_uint4(0u, 0u, 0u, 0u);
        if (!border && col >= 1 && col <= 56) {
            #pragma unroll
            for (int k = 0; k < 8; ++k)
                o.u[k] = t[(qq * 32 + oct * 8 + k) * TPAD + (col - 1)];
        }
        *(uint4*)&xt[(((size_t)(b * 16 + qq * 4 + oct)) * PLANEC
                      + (size_t)ihp * 58 + col) * 8] = o.v;
    }
}

// wmix [b][s=0..35][oc][32] bf16 + fused bmix.  (unchanged R7)
__global__ __launch_bounds__(256) void prep_wmix(
        const float* __restrict__ rw, const float* __restrict__ wgt,
        const float* __restrict__ bias,
        unsigned short* __restrict__ wmix, float* __restrict__ bmix) {
    __shared__ float wlds[KEXP * KTOT];     // 36.9 KB
    __shared__ float rwl[16 * KEXP];
    int oc  = blockIdx.x;
    int bg  = blockIdx.y;
    int tid = threadIdx.x;

    if (tid < 16 * KEXP) rwl[tid] = rw[bg * 16 * KEXP + tid];
    const float* wsrc = wgt + (size_t)oc * KTOT;
    #pragma unroll
    for (int e = 0; e < KEXP; ++e) {
        const float* we = wsrc + (size_t)e * OCH * KTOT;
        for (int j = tid; j < KTOT; j += 256) wlds[e * KTOT + j] = we[j];
    }
    __syncthreads();

    if (tid < 16) {
        float a = 0.f;
        #pragma unroll
        for (int e = 0; e < KEXP; ++e) a += rwl[tid * KEXP + e] * bias[e * OCH + oc];
        bmix[(size_t)(bg * 16 + tid) * OCH + oc] = a;
    }

    for (int t = tid; t < KTOT; t += 256) {
        int c = t & 127, rs = t >> 7;
        int q = c >> 5, cl = c & 31;
        size_t oidx = ((size_t)(q * 9 + rs) * OCH + oc) * 32 + cl;
        float w8[KEXP];
        #pragma unroll
        for (int e = 0; e < KEXP; ++e) w8[e] = wlds[e * KTOT + c * 9 + rs];
        #pragma unroll
        for (int b = 0; b < 16; ++b) {
            float a = 0.f;
            #pragma unroll
            for (int e = 0; e < KEXP; ++e) a += rwl[b * KEXP + e] * w8[e];
            wmix[(size_t)(bg * 16 + b) * WMIX_PS + oidx] = (unsigned short)f2bf(a);
        }
    }
}

// Block = (sample b = blk&63, 2-row tile), 256 threads = 4 waves, 2M x 2N:
//   wm = wave&1 owns oc [wm*64, wm*64+64)  (4 m-subtiles, A-dup 2)
//   wn = wave>>1 owns nt range wn*3 .. wn*3+3 (nt=3 computed by both, B-dup 2)
// B-LDS reads per k-step per block: 16 b128 (vs 28 in the 4M split) with
// acc[4][4]=64 AGPR -> ~144 unified regs -> 3 waves/SIMD, 3 blocks/CU.
// The two wn-waves of one wm read IDENTICAL A addresses back-to-back -> L1.
// Chunked x_t layout (R6/R7-proven): staging 4 linear gl16/wave; B-reads
// conflict-free. Double-buffered; stage(q+1) at top of compute(q).
__global__ __launch_bounds__(256, 3) void condconv_mfma(
        const unsigned short* __restrict__ xt, const unsigned short* __restrict__ wmix,
        const float* __restrict__ bmix, float* __restrict__ out) {
    __shared__ unsigned short patch[2][8192];   // 2 x 16,384 B

    int blk  = blockIdx.x;
    int b    = blk & 63;
    int tile = blk >> 6;               // 0..27
    int oh0  = tile * 2;
    int tid  = threadIdx.x;
    int wave = tid >> 6, lane = tid & 63, ln = lane & 15, quad = lane >> 4;
    int wm = wave & 1, wn = wave >> 1;

    // A: wmix[b][s][oc][32]; per-lane base (oc = wm*64 + mt*16 + ln, k-oct = quad)
    const unsigned short* ap = wmix + (size_t)b * WMIX_PS
                             + (size_t)(wm * 64 + ln) * 32 + quad * 8;

    const unsigned short* xb = xt + (size_t)(b * 16) * (PLANEC * 8)
                             + (size_t)oh0 * 58 * 8;

    // staging: wave w stages octet w; 4 gl16 of 64 chunks, clamp tail
    int rcl[4];
    #pragma unroll
    for (int i = 0; i < 4; ++i) {
        int rc = i * 64 + lane;
        rcl[i] = (rc > 231) ? 231 : rc;          // clamp into valid 232-chunk slab
    }

    // B bases + output offsets: n = (wn*3 + j)*16 + ln, j = 0..3
    int cb[4], offn[4];
    #pragma unroll
    for (int j = 0; j < 4; ++j) {
        int n   = (wn * 3 + j) * 16 + ln;
        int row = (n >= 56) ? 1 : 0;
        int ow  = n - row * 56;
        cb[j]   = (quad * 256 + row * 58 + ow) * 8;   // ushort index
        offn[j] = (oh0 + row) * HW + ow;
    }

    f32x4 acc[4][4] = {};

    auto stage = [&](int qq, int bf) {
        const unsigned short* sq = xb + (size_t)(qq * 4 + wave) * (PLANEC * 8);
        #pragma unroll
        for (int i = 0; i < 4; ++i)
            gl16(sq + (size_t)rcl[i] * 8, &patch[bf][(wave * 256 + i * 64) * 8]);
    };

    stage(0, 0);
    bf16x8 pa[2][4];
    #pragma unroll
    for (int mt = 0; mt < 4; ++mt) {
        pa[0][mt] = *(const bf16x8*)(ap + mt * 512);
        pa[1][mt] = *(const bf16x8*)(ap + 4096 + mt * 512);
    }
    __syncthreads();

    #pragma unroll
    for (int qq = 0; qq < 4; ++qq) {
        if (qq < 3) stage(qq + 1, (qq + 1) & 1);
        #pragma unroll
        for (int s9 = 0; s9 < 9; ++s9) {
            const int s = qq * 9 + s9;
            bf16x8 ca[4];
            #pragma unroll
            for (int mt = 0; mt < 4; ++mt) ca[mt] = pa[s & 1][mt];
            const int sp = (s + 2 < NSTEP) ? (s + 2) : (NSTEP - 1);
            #pragma unroll
            for (int mt = 0; mt < 4; ++mt)
                pa[s & 1][mt] = *(const bf16x8*)(ap + (size_t)sp * 4096 + mt * 512);
            const int r = s9 / 3, sc = s9 - r * 3;
            const int pshift = (r * 58 + sc) * 8;
            #pragma unroll
            for (int j = 0; j < 4; ++j) {
                bf16x8 bb = *(const bf16x8*)&patch[qq & 1][cb[j] + pshift];
                acc[0][j] = __builtin_amdgcn_mfma_f32_16x16x32_bf16(ca[0], bb, acc[0][j], 0, 0, 0);
                acc[1][j] = __builtin_amdgcn_mfma_f32_16x16x32_bf16(ca[1], bb, acc[1][j], 0, 0, 0);
                acc[2][j] = __builtin_amdgcn_mfma_f32_16x16x32_bf16(ca[2], bb, acc[2][j], 0, 0, 0);
                acc[3][j] = __builtin_amdgcn_mfma_f32_16x16x32_bf16(ca[3], bb, acc[3][j], 0, 0, 0);
            }
        }
        __syncthreads();
    }

    // epilogue: D layout col(lane&15)=pixel, row(quad*4+reg)=oc.
    // nt=3 is computed by both wn-halves; wn=1 skips j=0 to store it once.
    const float* bmb = bmix + b * OCH;
    float* ob = out + (size_t)b * OCH * HW * HW;
    #pragma unroll
    for (int mt = 0; mt < 4; ++mt) {
        #pragma unroll
        for (int rg = 0; rg < 4; ++rg) {
            int oc = wm * 64 + mt * 16 + quad * 4 + rg;
            float bv = bmb[oc];
            #pragma unroll
            for (int j = 0; j < 4; ++j) {
                if (wn == 1 && j == 0) continue;
                ob[(size_t)oc * (HW * HW) + offn[j]] = acc[mt][j][rg] + bv;
            }
        }
    }
}

extern "C" void kernel_launch(void* const* d_in, const int* in_sizes, int n_in,
                              void* d_out, int out_size, void* d_ws, size_t ws_size,
                              hipStream_t stream) {
    (void)in_sizes; (void)n_in; (void)out_size; (void)ws_size;
    const float* x    = (const float*)d_in[0];
    const float* rw   = (const float*)d_in[1];
    const float* wgt  = (const float*)d_in[2];
    const float* bias = (const float*)d_in[3];
    float* outp = (float*)d_out;

    // ws layout: wmix (18,874,368 B) | bmix (32 KB) | x_t (55,115,776 B)
    unsigned short* wmix = (unsigned short*)d_ws;
    float* bmix = (float*)((char*)d_ws + (size_t)BS * WMIX_PS * 2);
    unsigned short* xtw = (unsigned short*)((char*)d_ws + (size_t)BS * WMIX_PS * 2 + 32768);

    hipLaunchKernelGGL(prep_xt,   dim3(BS, 58), dim3(256), 0, stream, x, xtw);
    hipLaunchKernelGGL(prep_wmix, dim3(OCH, 4), dim3(256), 0, stream, rw, wgt, bias, wmix, bmix);
    hipLaunchKernelGGL(condconv_mfma, dim3(BS * 28), dim3(256), 0, stream,
                       xtw, wmix, bmix, outp);
}

// Round 9
// 269.048 us; speedup vs baseline: 1.1102x; 1.1102x over previous
//
#include <hip/hip_runtime.h>

#define BS    64
#define CIN   128
#define OCH   128
#define HW    56
#define KEXP  8
#define KTOT  1152             // 9 * 128
#define NSTEP 36               // k-steps of 32
#define PLANEC 3364            // 58*58 16B-chunks per (b,quarter,octet) plane
#define WMIX_PS (NSTEP * OCH * 32)   // 147456 elems per sample
#define TPAD  60               // prep_xt LDS row stride (8B-aligned rows)

typedef __bf16 bf16x8 __attribute__((ext_vector_type(8)));
typedef __bf16 bf16x4 __attribute__((ext_vector_type(4)));
typedef float  f32x4  __attribute__((ext_vector_type(4)));

__device__ __forceinline__ unsigned f2bf(float f) {
    union { float f; unsigned u; } v; v.f = f;
    unsigned r = v.u + 0x7fffu + ((v.u >> 16) & 1u);   // RNE
    return r >> 16;
}

__device__ __forceinline__ void gl16(const unsigned short* g, unsigned short* l) {
    __builtin_amdgcn_global_load_lds(
        (const __attribute__((address_space(1))) void*)g,
        (__attribute__((address_space(3))) void*)l, 16, 0, 0);
}

// x [64][128][56][56] f32 -> x_t [64][qq=4][oct=4][58][58] chunks of 16 B
// (chunk = 8 channels c = qq*32+oct*8+k, bf16, zero halos).  (R7-proven)
__global__ __launch_bounds__(256) void prep_xt(const float* __restrict__ x,
                                               unsigned short* __restrict__ xt) {
    __shared__ unsigned short t[CIN * TPAD];   // 15,360 B
    int b = blockIdx.x, ihp = blockIdx.y;      // ihp in [0,58)
    int tid = threadIdx.x;
    bool border = (ihp == 0) || (ihp == 57);
    if (!border) {
        int ih = ihp - 1;
        const float* xr = x + (size_t)b * CIN * HW * HW + (size_t)ih * HW;
        #pragma unroll
        for (int i7 = 0; i7 < 7; ++i7) {               // 1792 float4 = 7/thread
            int i = i7 * 256 + tid;
            int c = i / 14, w4 = i - c * 14;
            float4 v = *(const float4*)(xr + (size_t)c * (HW * HW) + w4 * 4);
            bf16x4 pk = { (__bf16)v.x, (__bf16)v.y, (__bf16)v.z, (__bf16)v.w };
            *(bf16x4*)&t[c * TPAD + w4 * 4] = pk;      // 8B aligned
        }
    }
    __syncthreads();
    for (int j = tid; j < 928; j += 256) {             // 4*4*58 chunks
        int qq = j / 232, rr = j - qq * 232;
        int oct = rr / 58, col = rr - oct * 58;
        union { unsigned short u[8]; uint4 v; } o;
        o.v = make_uint4(0u, 0u, 0u, 0u);
        if (!border && col >= 1 && col <= 56) {
            #pragma unroll
            for (int k = 0; k < 8; ++k)
                o.u[k] = t[(qq * 32 + oct * 8 + k) * TPAD + (col - 1)];
        }
        *(uint4*)&xt[(((size_t)(b * 16 + qq * 4 + oct)) * PLANEC
                      + (size_t)ihp * 58 + col) * 8] = o.v;
    }
}

// wmix [b][s=0..35][oc][32] bf16 + fused bmix.  (R7-proven)
__global__ __launch_bounds__(256) void prep_wmix(
        const float* __restrict__ rw, const float* __restrict__ wgt,
        const float* __restrict__ bias,
        unsigned short* __restrict__ wmix, float* __restrict__ bmix) {
    __shared__ float wlds[KEXP * KTOT];     // 36.9 KB
    __shared__ float rwl[16 * KEXP];
    int oc  = blockIdx.x;
    int bg  = blockIdx.y;
    int tid = threadIdx.x;

    if (tid < 16 * KEXP) rwl[tid] = rw[bg * 16 * KEXP + tid];
    const float* wsrc = wgt + (size_t)oc * KTOT;
    #pragma unroll
    for (int e = 0; e < KEXP; ++e) {
        const float* we = wsrc + (size_t)e * OCH * KTOT;
        for (int j = tid; j < KTOT; j += 256) wlds[e * KTOT + j] = we[j];
    }
    __syncthreads();

    if (tid < 16) {
        float a = 0.f;
        #pragma unroll
        for (int e = 0; e < KEXP; ++e) a += rwl[tid * KEXP + e] * bias[e * OCH + oc];
        bmix[(size_t)(bg * 16 + tid) * OCH + oc] = a;
    }

    for (int t = tid; t < KTOT; t += 256) {
        int c = t & 127, rs = t >> 7;
        int q = c >> 5, cl = c & 31;
        size_t oidx = ((size_t)(q * 9 + rs) * OCH + oc) * 32 + cl;
        float w8[KEXP];
        #pragma unroll
        for (int e = 0; e < KEXP; ++e) w8[e] = wlds[e * KTOT + c * 9 + rs];
        #pragma unroll
        for (int b = 0; b < 16; ++b) {
            float a = 0.f;
            #pragma unroll
            for (int e = 0; e < KEXP; ++e) a += rwl[b * KEXP + e] * w8[e];
            wmix[(size_t)(bg * 16 + b) * WMIX_PS + oidx] = (unsigned short)f2bf(a);
        }
    }
}

// R6-EXACT condconv (best measured structure): block = (sample b = blk&63,
// 2-row tile), 256 threads = 4 waves, wave owns 32 oc (2 m-subtiles),
// acc[2][7] = 120 unified regs, depth-2 A pipeline from XCD-local L2,
// chunked x_t staging (4 linear gl16/wave), conflict-free ds_read_b128
// B-fragments, double-buffered (2 x 16,384 B).
__global__ __launch_bounds__(256, 4) void condconv_mfma(
        const unsigned short* __restrict__ xt, const unsigned short* __restrict__ wmix,
        const float* __restrict__ bmix, float* __restrict__ out) {
    __shared__ unsigned short patch[2][8192];   // 2 x 16,384 B

    int blk  = blockIdx.x;
    int b    = blk & 63;
    int tile = blk >> 6;               // 0..27
    int oh0  = tile * 2;
    int tid  = threadIdx.x;
    int wave = tid >> 6, lane = tid & 63, ln = lane & 15, quad = lane >> 4;

    // A: wmix[b][s][oc][32]; per-lane base (oc = wave*32 + ln, k-oct = quad)
    const unsigned short* ap = wmix + (size_t)b * WMIX_PS
                             + (size_t)(wave * 32 + ln) * 32 + quad * 8;

    const unsigned short* xb = xt + (size_t)(b * 16) * (PLANEC * 8)
                             + (size_t)oh0 * 58 * 8;

    // staging: wave w stages octet w; 4 gl16 of 64 chunks, clamp tail
    int rcl[4];
    #pragma unroll
    for (int i = 0; i < 4; ++i) {
        int rc = i * 64 + lane;
        rcl[i] = (rc > 231) ? 231 : rc;          // clamp into valid 232-chunk slab
    }

    // B bases + output offsets: n = nt*16 + ln  (N=112 exact)
    int cb[7], offn[7];
    #pragma unroll
    for (int nt = 0; nt < 7; ++nt) {
        int n   = nt * 16 + ln;
        int row = (n >= 56) ? 1 : 0;
        int ow  = n - row * 56;
        cb[nt]   = (quad * 256 + row * 58 + ow) * 8;   // ushort index
        offn[nt] = (oh0 + row) * HW + ow;
    }

    f32x4 acc[2][7] = {};

    auto stage = [&](int qq, int bf) {
        const unsigned short* sq = xb + (size_t)(qq * 4 + wave) * (PLANEC * 8);
        #pragma unroll
        for (int i = 0; i < 4; ++i)
            gl16(sq + (size_t)rcl[i] * 8, &patch[bf][(wave * 256 + i * 64) * 8]);
    };

    stage(0, 0);
    bf16x8 pa0[2], pa1[2];
    pa0[0] = *(const bf16x8*)(ap);
    pa1[0] = *(const bf16x8*)(ap + 512);
    pa0[1] = *(const bf16x8*)(ap + 4096);
    pa1[1] = *(const bf16x8*)(ap + 4096 + 512);
    __syncthreads();

    #pragma unroll
    for (int qq = 0; qq < 4; ++qq) {
        if (qq < 3) stage(qq + 1, (qq + 1) & 1);
        #pragma unroll
        for (int s9 = 0; s9 < 9; ++s9) {
            const int s = qq * 9 + s9;
            bf16x8 ca0 = pa0[s & 1], ca1 = pa1[s & 1];
            const int sp = (s + 2 < NSTEP) ? (s + 2) : (NSTEP - 1);
            pa0[s & 1] = *(const bf16x8*)(ap + (size_t)sp * 4096);
            pa1[s & 1] = *(const bf16x8*)(ap + (size_t)sp * 4096 + 512);
            const int r = s9 / 3, sc = s9 - r * 3;
            const int pshift = (r * 58 + sc) * 8;
            #pragma unroll
            for (int nt = 0; nt < 7; ++nt) {
                bf16x8 bb = *(const bf16x8*)&patch[qq & 1][cb[nt] + pshift];
                acc[0][nt] = __builtin_amdgcn_mfma_f32_16x16x32_bf16(ca0, bb, acc[0][nt], 0, 0, 0);
                acc[1][nt] = __builtin_amdgcn_mfma_f32_16x16x32_bf16(ca1, bb, acc[1][nt], 0, 0, 0);
            }
        }
        __syncthreads();
    }

    // epilogue: D layout col(lane&15)=pixel, row(quad*4+reg)=oc
    const float* bmb = bmix + b * OCH;
    float* ob = out + (size_t)b * OCH * HW * HW;
    #pragma unroll
    for (int mt = 0; mt < 2; ++mt) {
        #pragma unroll
        for (int rg = 0; rg < 4; ++rg) {
            int oc = wave * 32 + mt * 16 + quad * 4 + rg;
            float bv = bmb[oc];
            #pragma unroll
            for (int nt = 0; nt < 7; ++nt)
                ob[(size_t)oc * (HW * HW) + offn[nt]] = acc[mt][nt][rg] + bv;
        }
    }
}

extern "C" void kernel_launch(void* const* d_in, const int* in_sizes, int n_in,
                              void* d_out, int out_size, void* d_ws, size_t ws_size,
                              hipStream_t stream) {
    (void)in_sizes; (void)n_in; (void)out_size; (void)ws_size;
    const float* x    = (const float*)d_in[0];
    const float* rw   = (const float*)d_in[1];
    const float* wgt  = (const float*)d_in[2];
    const float* bias = (const float*)d_in[3];
    float* outp = (float*)d_out;

    // ws layout: wmix (18,874,368 B) | bmix (32 KB) | x_t (55,115,776 B)
    unsigned short* wmix = (unsigned short*)d_ws;
    float* bmix = (float*)((char*)d_ws + (size_t)BS * WMIX_PS * 2);
    unsigned short* xtw = (unsigned short*)((char*)d_ws + (size_t)BS * WMIX_PS * 2 + 32768);

    hipLaunchKernelGGL(prep_xt,   dim3(BS, 58), dim3(256), 0, stream, x, xtw);
    hipLaunchKernelGGL(prep_wmix, dim3(OCH, 4), dim3(256), 0, stream, rw, wgt, bias, wmix, bmix);
    hipLaunchKernelGGL(condconv_mfma, dim3(BS * 28), dim3(256), 0, stream,
                       xtw, wmix, bmix, outp);
}